// Round 1
// baseline (696.016 us; speedup 1.0000x reference)
//
#include <hip/hip_runtime.h>
#include <cstdint>

// Problem constants
#define NN 8192      // nodes
#define FF 512       // input features
#define FO 64        // per-head output features
#define NH 8         // heads
#define LDVT 8192    // V_t row stride (elements) -- V_t is (640 rows x 8192 k) bf16
#define LDYE 640     // Y row stride (elements)
#define YPART (8192 * 640)

typedef __attribute__((ext_vector_type(8))) __bf16 bf16x8;
typedef __attribute__((ext_vector_type(4))) float f32x4;

__device__ __forceinline__ unsigned short f2bf(float f) {
    // round-to-nearest-even f32 -> bf16 bits
    unsigned int u = __float_as_uint(f);
    u += 0x7fffu + ((u >> 16) & 1u);
    return (unsigned short)(u >> 16);
}

__device__ __forceinline__ void gload16(const void* g, void* l) {
    // async global->LDS, 16B per lane (emits global_load_lds_dwordx4)
    __builtin_amdgcn_global_load_lds(
        (const __attribute__((address_space(1))) unsigned int*)g,
        (__attribute__((address_space(3))) unsigned int*)l,
        16, 0, 0);
}

// ---------------------------------------------------------------------------
// K0: convert A (fp32, values in {0.0,1.0} -- exact in bf16) to bf16.
// 8 floats in -> 8 bf16 out per thread. Truncation is exact for 0.0/1.0.
// ---------------------------------------------------------------------------
__global__ __launch_bounds__(256) void k_convA(const uint4* __restrict__ A,
                                               uint4* __restrict__ Ab) {
    size_t i = (size_t)blockIdx.x * 256 + threadIdx.x;
    uint4 a = A[2 * i];
    uint4 b = A[2 * i + 1];
    uint4 o;
    o.x = (a.x >> 16) | (a.y & 0xffff0000u);
    o.y = (a.z >> 16) | (a.w & 0xffff0000u);
    o.z = (b.x >> 16) | (b.y & 0xffff0000u);
    o.w = (b.z >> 16) | (b.w & 0xffff0000u);
    Ab[i] = o;
}

// ---------------------------------------------------------------------------
// K1: per (head, 64-node tile): WX = X @ kernels[h] in fp32, s2 = WX . a2,
// e = exp(s2)  (s2 in ~[-3,3], no max-shift needed), then write
// V_t[h*64+o][m] = bf16(e[m]*WX[m][o])  and  V_t[512+h][m] = bf16(e[m]).
// V_t is n-major with k contiguous => GEMM B-operand loads are k-contiguous.
// ---------------------------------------------------------------------------
union K1Smem {
    struct { float Xs[64][68]; float Ks[64][68]; } s;                     // 34.8 KB
    struct { float red[64][16]; float es[64]; unsigned short Vs[64][72]; } r;
};

__global__ __launch_bounds__(256) void k_buildV(const float* __restrict__ X,
                                                const float* __restrict__ Kw,
                                                const float* __restrict__ Aw,
                                                unsigned short* __restrict__ Vt) {
    __shared__ K1Smem sm;
    const int t = threadIdx.x;
    const int n0 = blockIdx.x * 64;   // node tile base
    const int h = blockIdx.y;
    const int tr = t >> 4;            // 0..15: row group
    const int tc = t & 15;            // 0..15: col group (owns cols 4*tc..4*tc+3)

    float acc[4][4] = {};             // rows {tr+16i}, cols {4tc+j}

    for (int f0 = 0; f0 < FF; f0 += 64) {
        if (f0) __syncthreads();
        for (int j = 0; j < 4; ++j) {
            int fid = t + j * 256;
            int row = fid >> 4, c4 = fid & 15;
            *(float4*)&sm.s.Xs[row][c4 * 4] =
                *(const float4*)(X + (size_t)(n0 + row) * FF + f0 + c4 * 4);
            *(float4*)&sm.s.Ks[row][c4 * 4] =
                *(const float4*)(Kw + (size_t)h * FF * FO + (size_t)(f0 + row) * FO + c4 * 4);
        }
        __syncthreads();
        for (int k = 0; k < 64; ++k) {
            float4 b = *(const float4*)&sm.s.Ks[k][tc * 4];
            float a0 = sm.s.Xs[tr][k];
            float a1 = sm.s.Xs[tr + 16][k];
            float a2 = sm.s.Xs[tr + 32][k];
            float a3 = sm.s.Xs[tr + 48][k];
            acc[0][0] += a0 * b.x; acc[0][1] += a0 * b.y; acc[0][2] += a0 * b.z; acc[0][3] += a0 * b.w;
            acc[1][0] += a1 * b.x; acc[1][1] += a1 * b.y; acc[1][2] += a1 * b.z; acc[1][3] += a1 * b.w;
            acc[2][0] += a2 * b.x; acc[2][1] += a2 * b.y; acc[2][2] += a2 * b.z; acc[2][3] += a2 * b.w;
            acc[3][0] += a3 * b.x; acc[3][1] += a3 * b.y; acc[3][2] += a3 * b.z; acc[3][3] += a3 * b.w;
        }
    }
    __syncthreads();   // done with Xs/Ks; union region reused below

    // s2 partials: per (row, tc), dot of this thread's 4 cols with a2
    float4 a2v = *(const float4*)(Aw + h * 128 + 64 + tc * 4);
    for (int i = 0; i < 4; ++i)
        sm.r.red[i * 16 + tr][tc] =
            acc[i][0] * a2v.x + acc[i][1] * a2v.y + acc[i][2] * a2v.z + acc[i][3] * a2v.w;
    __syncthreads();
    if (t < 64) {
        float s = 0.f;
        for (int c = 0; c < 16; ++c) s += sm.r.red[t][c];
        sm.r.es[t] = __expf(s);
    }
    __syncthreads();
    float ev[4];
    for (int i = 0; i < 4; ++i) ev[i] = sm.r.es[i * 16 + tr];
    // transpose V tile through LDS so global writes are k-contiguous
    for (int i = 0; i < 4; ++i)
        for (int j = 0; j < 4; ++j)
            sm.r.Vs[tc * 4 + j][i * 16 + tr] = f2bf(ev[i] * acc[i][j]);
    __syncthreads();
    for (int j2 = 0; j2 < 2; ++j2) {
        int vid = t + j2 * 256;
        int o = vid >> 3, c = vid & 7;
        *(uint4*)(Vt + (size_t)(h * 64 + o) * LDVT + n0 + c * 8) =
            *(const uint4*)&sm.r.Vs[o][c * 8];
    }
    if (t < 64) Vt[(size_t)(512 + h) * LDVT + n0 + t] = f2bf(sm.r.es[t]);
    // rows 520..639 of V_t stay poisoned (~1e-13 magnitude) -> Y cols 520..639
    // are garbage but never read by the epilogue.
}

// ---------------------------------------------------------------------------
// K2: Y = A_bf16 (8192x8192) @ V_t^T (8192x640), bf16 MFMA, fp32 acc.
// BM=128, BN=160, BK=32; 4 waves in 2x2; wave tile 64x80 (4x5 MFMA tiles).
// Split-K = 3 (grid.z) into separate Y buffers -> 768 blocks = 3/CU.
// LDS layout: 16B granules, column-major by kq: granule g = kq*M + m.
// MFMA A/B fragment = 8 contiguous k at (m|n = lane&15, kq = lane>>4).
// ---------------------------------------------------------------------------
__global__ __launch_bounds__(256) void k_gemm(const unsigned short* __restrict__ Ab,
                                              const unsigned short* __restrict__ Vt,
                                              float* __restrict__ Y) {
    __shared__ unsigned short As[4096];   // 128 rows * 32 k = 512 granules, 8 KB
    __shared__ unsigned short Bs[5120];   // 160 rows * 32 k = 640 granules, 10 KB
    const int t = threadIdx.x;
    const int ct = blockIdx.x;    // 0..3   (col tile, 160 V-rows)
    const int rt = blockIdx.y;    // 0..63  (row tile, 128 A-rows)
    const int part = blockIdx.z;  // 0..2   (k split)
    const int ks0 = (part * 256) / 3;
    const int ks1 = ((part + 1) * 256) / 3;

    // staging source/dest (all linear in k -> precompute once)
    const int ga0 = t, ga1 = t + 256;
    const unsigned short* aS0 = Ab + ((size_t)(rt * 128 + (ga0 & 127)) << 13) + (ga0 >> 7) * 8;
    const unsigned short* aS1 = Ab + ((size_t)(rt * 128 + (ga1 & 127)) << 13) + (ga1 >> 7) * 8;
    unsigned short* aD0 = As + ga0 * 8;
    unsigned short* aD1 = As + ga1 * 8;

    const int gb0 = t, gb1 = t + 256, gb2 = t + 512;
    const int nb0 = gb0 % 160, kq0 = gb0 / 160;
    const int nb1 = gb1 % 160, kq1 = gb1 / 160;
    const int nb2 = gb2 % 160, kq2 = gb2 / 160;
    const unsigned short* bS0 = Vt + ((size_t)(ct * 160 + nb0) << 13) + kq0 * 8;
    const unsigned short* bS1 = Vt + ((size_t)(ct * 160 + nb1) << 13) + kq1 * 8;
    const unsigned short* bS2 = Vt + ((size_t)(ct * 160 + nb2) << 13) + kq2 * 8;
    unsigned short* bD0 = Bs + gb0 * 8;
    unsigned short* bD1 = Bs + gb1 * 8;
    unsigned short* bD2 = Bs + gb2 * 8;

    const int lane = t & 63;
    const int w = t >> 6;
    const int wm = w >> 1, wn = w & 1;
    const int quad = lane >> 4, l15 = lane & 15;

    const bf16x8* aF[4];
    const bf16x8* bF[5];
    for (int i = 0; i < 4; ++i)
        aF[i] = (const bf16x8*)(As + (size_t)(quad * 128 + wm * 64 + i * 16 + l15) * 8);
    for (int j = 0; j < 5; ++j)
        bF[j] = (const bf16x8*)(Bs + (size_t)(quad * 160 + wn * 80 + j * 16 + l15) * 8);

    f32x4 acc[4][5] = {};

    for (int ks = ks0; ks < ks1; ++ks) {
        const int ko = ks * 32;
        gload16(aS0 + ko, aD0);
        gload16(aS1 + ko, aD1);
        gload16(bS0 + ko, bD0);
        gload16(bS1 + ko, bD1);
        if (t < 128) gload16(bS2 + ko, bD2);
        __syncthreads();   // drains vmcnt (barrier semantics)
        bf16x8 av[4], bv[5];
        for (int i = 0; i < 4; ++i) av[i] = aF[i][0];
        for (int j = 0; j < 5; ++j) bv[j] = bF[j][0];
        for (int i = 0; i < 4; ++i)
            for (int j = 0; j < 5; ++j)
                acc[i][j] = __builtin_amdgcn_mfma_f32_16x16x32_bf16(av[i], bv[j], acc[i][j], 0, 0, 0);
        __syncthreads();   // protect LDS from next iteration's staging
    }

    // C/D layout: col = lane&15, row = (lane>>4)*4 + reg  [m89/m91 verified]
    float* Yp = Y + (size_t)part * YPART;
    for (int i = 0; i < 4; ++i) {
        int row = rt * 128 + wm * 64 + i * 16 + quad * 4;
        for (int j = 0; j < 5; ++j) {
            int col = ct * 160 + wn * 80 + j * 16 + l15;
            for (int r = 0; r < 4; ++r)
                Yp[(size_t)(row + r) * LDYE + col] = acc[i][j][r];
        }
    }
}

// ---------------------------------------------------------------------------
// K3: out[n, h*64+o] = relu( sum_p Ynum / sum_p Yden )
// ---------------------------------------------------------------------------
__global__ __launch_bounds__(256) void k_epi(const float* __restrict__ Y,
                                             float* __restrict__ out) {
    int idx = blockIdx.x * 256 + threadIdx.x;   // one float4 of out each
    int n = idx >> 7;
    int c = (idx & 127) * 4;
    int h = c >> 6;
    const float* y0 = Y + (size_t)n * LDYE;
    const float* y1 = y0 + (size_t)YPART;
    const float* y2 = y1 + (size_t)YPART;
    float4 u0 = *(const float4*)(y0 + c);
    float4 u1 = *(const float4*)(y1 + c);
    float4 u2 = *(const float4*)(y2 + c);
    float den = y0[512 + h] + y1[512 + h] + y2[512 + h];
    float inv = 1.0f / den;
    float4 o;
    o.x = fmaxf((u0.x + u1.x + u2.x) * inv, 0.f);
    o.y = fmaxf((u0.y + u1.y + u2.y) * inv, 0.f);
    o.z = fmaxf((u0.z + u1.z + u2.z) * inv, 0.f);
    o.w = fmaxf((u0.w + u1.w + u2.w) * inv, 0.f);
    *(float4*)(out + (size_t)n * 512 + c) = o;
}

extern "C" void kernel_launch(void* const* d_in, const int* in_sizes, int n_in,
                              void* d_out, int out_size, void* d_ws, size_t ws_size,
                              hipStream_t stream) {
    const float* X  = (const float*)d_in[0];   // (8192, 512)
    const float* A  = (const float*)d_in[1];   // (8192, 8192)
    const float* Kw = (const float*)d_in[2];   // (8, 512, 64)
    const float* Aw = (const float*)d_in[3];   // (8, 128)
    float* out = (float*)d_out;                // (8192, 512)
    char* ws = (char*)d_ws;
    // ws layout: A_bf16 128 MiB | V_t 10 MiB | Y parts 3 * 20 MiB  (~198 MiB)
    unsigned short* Ab = (unsigned short*)ws;
    unsigned short* Vt = (unsigned short*)(ws + (size_t)134217728);
    float* Yb = (float*)(ws + (size_t)134217728 + (size_t)10485760);

    k_convA<<<dim3(32768), dim3(256), 0, stream>>>((const uint4*)A, (uint4*)Ab);
    k_buildV<<<dim3(128, 8), dim3(256), 0, stream>>>(X, Kw, Aw, Vt);
    k_gemm<<<dim3(4, 64, 3), dim3(256), 0, stream>>>(Ab, Vt, Yb);
    k_epi<<<dim3(4096), dim3(256), 0, stream>>>(Yb, out);
}